// Round 6
// baseline (433.639 us; speedup 1.0000x reference)
//
#include <hip/hip_runtime.h>
#include <math.h>

#define HEADS 8
#define DIM   64
#define DK    24
#define DHK   3
#define BB    4
#define HH    128
#define WW    128
#define NN    (HH*WW)
#define QSCALE 0.125f

// ---------------------------------------------------------------------------
// mega: single fused kernel. grid 1024 (4b x 256 8x8-tiles) x 192 thr.
// Co-residency proof: __launch_bounds__(192,4) -> VGPR<=128 -> >=16 waves/CU;
// LDS 27328B -> 5 blocks/CU; capacity 5*256=1280 >= 1024 grid => all blocks
// resident => spin-waits cannot deadlock.
// Sync: R2-PROVEN release/acquire (threadfence + device atomics). R3's
// cooperative launch (silent no-op) is NOT used.
// Phases per block:
//   S:  tile's 64 tokens ARE 64 Sp-tokens: acc outer-product imap x x,
//       atomicAdd into Sp_part[b*64 + chunk/4] (4-way contention),
//       fence, cnt[b]++.
//   A:  (chunk 8..15) spin cnt[b]==256; reduce 8 slabs -> atomicAdd Sp2[b];
//       fence, done1[b]++.
//   B:  (chunk 0..7, h=chunk) spin done1[b]==8; K2-proven attention body
//       (3 waves exactly); atomicAdd Pt[b]; fence, done2[b]++.
//   ph1/ph2: conv kproj + conv1+gelu (R4-proven 48us body, Pt-independent
//       -> overlaps the attention tail).
//   ph3: spin done2[b]==8; proj fea@Pt + conv2 (R4-proven body).
// ---------------------------------------------------------------------------
__global__ __launch_bounds__(192, 4) void mega(
    const float* __restrict__ x,       // [B*N,64]
    const float* __restrict__ fea,     // [B*N,64]
    const float* __restrict__ imap,    // [B*N,24]
    const float* __restrict__ Wq,      // [64,512]
    const float* __restrict__ Wk,      // [24,24]
    const float* __restrict__ Wv,      // [64,512]
    const float* __restrict__ rescale, // [8]
    const float* __restrict__ Wp,      // [24,24]
    const float* __restrict__ bp,      // [24]
    const float* __restrict__ c1w,     // [24,8,3,3]
    const float* __restrict__ c2w,     // [24,8,3,3]
    float* __restrict__ Sp_part,       // [256,1536] zeroed
    float* __restrict__ Sp2,           // [4,1536]  zeroed
    float* __restrict__ Pt,            // [4,1536]  zeroed
    int* __restrict__ sync_,           // [12] zeroed: cnt[4],done1[4],done2[4]
    float* __restrict__ outp)          // [B,H,W,24]
{
    __shared__ __align__(16) float smem[6832];  // conv: kbuf[4032]+y1l[2800]
    int* cnt   = sync_;
    int* done1 = sync_ + 4;
    int* done2 = sync_ + 8;

    const int tid = threadIdx.x;
    const int blk = blockIdx.x;
    const int b = blk >> 8, chunk = blk & 255;
    const int ti = chunk >> 4, tj = chunk & 15;
    const int i0 = ti * 8, j0 = tj * 8;

    // ================= S: Sp partial for this tile's 64 tokens =============
    {
        const int i24 = tid % 24, c8 = tid / 24;   // 24 x 8 = 192
        float av[8];
        #pragma unroll
        for (int q = 0; q < 8; ++q) av[q] = 0.f;
        const long pix0 = ((long)(b * HH + i0)) * WW + j0;
        for (int r = 0; r < 8; ++r) {
            const float* xr = x    + (pix0 + r * WW) * 64 + c8 * 8;
            const float* mr = imap + (pix0 + r * WW) * 24 + i24;
            #pragma unroll
            for (int cc = 0; cc < 8; ++cc) {
                float mv = mr[cc * 24];
                float4 u = *(const float4*)(xr + cc * 64);
                float4 v = *(const float4*)(xr + cc * 64 + 4);
                av[0] += mv * u.x; av[1] += mv * u.y;
                av[2] += mv * u.z; av[3] += mv * u.w;
                av[4] += mv * v.x; av[5] += mv * v.y;
                av[6] += mv * v.z; av[7] += mv * v.w;
            }
        }
        float* sp = Sp_part + ((long)(b * 64 + (chunk >> 2))) * 1536 + i24 * 64 + c8 * 8;
        #pragma unroll
        for (int q = 0; q < 8; ++q) atomicAdd(sp + q, av[q]);
    }
    __threadfence();                  // release our Sp atomics/stores
    __syncthreads();
    if (tid == 0) atomicAdd(&cnt[b], 1);

    // ================= A: octant slab reduce -> Sp2 =========================
    if (chunk >= 8 && chunk < 16) {
        if (tid == 0)
            while (__hip_atomic_load(&cnt[b], __ATOMIC_RELAXED, __HIP_MEMORY_SCOPE_AGENT) < 256)
                __builtin_amdgcn_s_sleep(4);
        __syncthreads();
        __threadfence();              // acquire
        const int o8 = chunk - 8;
        const float* p = Sp_part + ((long)(b * 64 + o8 * 8)) * 1536 + tid * 8;
        float a2[8];
        #pragma unroll
        for (int q = 0; q < 8; ++q) a2[q] = 0.f;
        #pragma unroll
        for (int pb = 0; pb < 8; ++pb) {
            float4 u = *(const float4*)(p + (long)pb * 1536);
            float4 v = *(const float4*)(p + (long)pb * 1536 + 4);
            a2[0] += u.x; a2[1] += u.y; a2[2] += u.z; a2[3] += u.w;
            a2[4] += v.x; a2[5] += v.y; a2[6] += v.z; a2[7] += v.w;
        }
        float* s2 = Sp2 + b * 1536 + tid * 8;
        #pragma unroll
        for (int q = 0; q < 8; ++q) atomicAdd(s2 + q, a2[q]);
        __threadfence();
        __syncthreads();
        if (tid == 0) atomicAdd(&done1[b], 1);
    }
    // ================= B: attention for (b, h=chunk) ========================
    else if (chunk < 8) {
        const int h = chunk;
        if (tid == 0)
            while (__hip_atomic_load(&done1[b], __ATOMIC_RELAXED, __HIP_MEMORY_SCOPE_AGENT) < 8)
                __builtin_amdgcn_s_sleep(4);
        __syncthreads();
        __threadfence();              // acquire
        float* Sp_l = smem;           // 1536
        float* sS   = smem + 1536;    // 192 (reused for M)
        float* sP   = smem + 1760;    // 192
        float* Wv_l = smem + 1984;    // 64*65 = 4160 -> ends 6144 <= 6832
        for (int e = tid; e < 1536; e += 192) Sp_l[e] = Sp2[b * 1536 + e];
        for (int e = tid; e < 4096; e += 192) {
            int c = e >> 6, d = e & 63;
            Wv_l[c * 65 + d] = Wv[c * 512 + h * 64 + d];
        }
        __syncthreads();

        const int w3 = tid >> 6, lane = tid & 63;   // exactly 3 waves
        {   // S[ch,c] = sum_i Wk[i,ch]*Sp[i,c]
            const float* wk = Wk + (h * 3 + w3);
            float s = 0.f;
            #pragma unroll
            for (int i = 0; i < 24; ++i) s += wk[i * 24] * Sp_l[i * 64 + lane];
            sS[w3 * 64 + lane] = s;
        }
        __syncthreads();
        {   // att row + wave-parallel softmax over d = lane
            const float* sr = sS + w3 * 64;
            float a = 0.f;
            #pragma unroll 8
            for (int c = 0; c < 64; ++c) a += sr[c] * Wq[c * 512 + h * 64 + lane];
            a *= QSCALE * rescale[h];
            float mx = a;
            #pragma unroll
            for (int off = 32; off >= 1; off >>= 1)
                mx = fmaxf(mx, __shfl_xor(mx, off, 64));
            float e = expf(a - mx);
            float sum = e;
            #pragma unroll
            for (int off = 32; off >= 1; off >>= 1)
                sum += __shfl_xor(sum, off, 64);
            sP[w3 * 64 + lane] = e / sum;
        }
        __syncthreads();
        {   // M[ch,c] = sum_d P[ch,d]*Wv[c,h*64+d]; reuse sS
            const float* pr = sP + w3 * 64;
            const float* wv = Wv_l + lane * 65;
            float m = 0.f;
            #pragma unroll
            for (int d = 0; d < 64; ++d) m += pr[d] * wv[d];
            sS[w3 * 64 + lane] = m;
        }
        __syncthreads();
        for (int q = tid; q < 1536; q += 192) {
            int o = q >> 6, c = q & 63;
            float v = 0.f;
            #pragma unroll
            for (int k = 0; k < 3; ++k)
                v += sS[k * 64 + c] * Wp[(k * 8 + h) * 24 + o];
            atomicAdd(&Pt[b * 1536 + o * 64 + c], v);
        }
        __threadfence();
        __syncthreads();
        if (tid == 0) atomicAdd(&done2[b], 1);
        __syncthreads();              // smem reused by ph1 below
    }

    // ================= ph1: kproj on 12x12 halo (R4 body) ===================
    float* kbuf = smem;               // 144*28 = 4032
    float* y1l  = smem + 4032;        // 100*28 = 2800
    const int o = tid % 24, jj = tid / 24;
    const int g = o >> 3;

    if (tid < 144) {
        const int pi = tid / 12, pj = tid % 12;
        const int gi = i0 + pi - 2, gj = j0 + pj - 2;
        float kv[24];
        #pragma unroll
        for (int j = 0; j < 24; ++j) kv[j] = 0.f;
        if (gi >= 0 && gi < HH && gj >= 0 && gj < WW) {
            const float4* m4 = (const float4*)(imap + (((long)b * HH + gi) * WW + gj) * 24);
            float m[24];
            #pragma unroll
            for (int i = 0; i < 6; ++i) {
                float4 v = m4[i];
                m[4*i+0]=v.x; m[4*i+1]=v.y; m[4*i+2]=v.z; m[4*i+3]=v.w;
            }
            for (int i = 0; i < 24; ++i) {
                float mi = m[i];
                #pragma unroll
                for (int j = 0; j < 24; ++j) kv[j] += mi * Wk[i * 24 + j];
            }
        }
        #pragma unroll
        for (int j = 0; j < 24; ++j) kbuf[tid * 28 + j] = kv[j];
    }
    __syncthreads();

    // ================= ph2: y1 = gelu(conv1) (R4 body) ======================
    {
        float wr[8][9];
        {
            const float4* wp = (const float4*)(c1w + o * 72);
            #pragma unroll
            for (int t = 0; t < 18; ++t) ((float4*)wr)[t] = wp[t];
        }
        for (int task = tid; task < 240; task += 192) {
            const int r = task / 24;
            float wc[3][3][8];
            #pragma unroll
            for (int slot = 0; slot < 2; ++slot)
                #pragma unroll
                for (int di = 0; di < 3; ++di) {
                    const float* p = kbuf + ((r + di) * 12 + slot) * 28 + g * 8;
                    *(float4*)&wc[slot][di][0] = *(const float4*)(p);
                    *(float4*)&wc[slot][di][4] = *(const float4*)(p + 4);
                }
            #pragma unroll
            for (int c = 0; c < 10; ++c) {
                const int s2 = (c + 2) % 3;
                #pragma unroll
                for (int di = 0; di < 3; ++di) {
                    const float* p = kbuf + ((r + di) * 12 + (c + 2)) * 28 + g * 8;
                    *(float4*)&wc[s2][di][0] = *(const float4*)(p);
                    *(float4*)&wc[s2][di][4] = *(const float4*)(p + 4);
                }
                float s = 0.f;
                #pragma unroll
                for (int dj = 0; dj < 3; ++dj) {
                    const int sl = (c + dj) % 3;
                    #pragma unroll
                    for (int di = 0; di < 3; ++di)
                        #pragma unroll
                        for (int ic = 0; ic < 8; ++ic)
                            s += wc[sl][di][ic] * wr[ic][di * 3 + dj];
                }
                const int gi = i0 + r - 1, gj = j0 + c - 1;
                float val = 0.f;
                if (gi >= 0 && gi < HH && gj >= 0 && gj < WW)
                    val = 0.5f * s * (1.f + erff(s * 0.70710678f));
                y1l[(r * 10 + c) * 28 + o] = val;
            }
        }
    }
    __syncthreads();

    // ================= wait for Pt, then ph3 (R4 body) ======================
    if (tid == 0)
        while (__hip_atomic_load(&done2[b], __ATOMIC_RELAXED, __HIP_MEMORY_SCOPE_AGENT) < 8)
            __builtin_amdgcn_s_sleep(4);
    __syncthreads();
    __threadfence();                  // acquire Pt

    float wr[8][9];
    {
        const float4* wp = (const float4*)(c2w + o * 72);
        #pragma unroll
        for (int t = 0; t < 18; ++t) ((float4*)wr)[t] = wp[t];
    }

    float acc[8];
    {
        const float bo = bp[o];
        #pragma unroll
        for (int ii = 0; ii < 8; ++ii) acc[ii] = bo;
        const float* PtRow = Pt + b * 1536 + o * 64;
        const float* feaB = fea + (((long)(b * HH + i0)) * WW + (j0 + jj)) * 64;
        for (int cq = 0; cq < 16; ++cq) {
            float4 p = *(const float4*)(PtRow + cq * 4);
            #pragma unroll
            for (int ii = 0; ii < 8; ++ii) {
                float4 f = *(const float4*)(feaB + (long)ii * WW * 64 + cq * 4);
                acc[ii] += f.x * p.x + f.y * p.y + f.z * p.z + f.w * p.w;
            }
        }
    }

    float win[3][3][8];
    #define LROW(R, SLOT)                                                     \
    {                                                                         \
        const float* rp_ = y1l + ((R) * 10 + jj) * 28 + g * 8;                \
        *(float4*)&win[SLOT][0][0] = *(const float4*)(rp_);                   \
        *(float4*)&win[SLOT][0][4] = *(const float4*)(rp_ + 4);               \
        *(float4*)&win[SLOT][1][0] = *(const float4*)(rp_ + 28);              \
        *(float4*)&win[SLOT][1][4] = *(const float4*)(rp_ + 32);              \
        *(float4*)&win[SLOT][2][0] = *(const float4*)(rp_ + 56);              \
        *(float4*)&win[SLOT][2][4] = *(const float4*)(rp_ + 60);              \
    }

    LROW(0, 0)
    LROW(1, 1)
    #pragma unroll
    for (int ii = 0; ii < 8; ++ii) {
        LROW(ii + 2, (ii + 2) % 3)
        float s = 0.f;
        #pragma unroll
        for (int di = 0; di < 3; ++di) {
            const int slot = (ii + di) % 3;
            #pragma unroll
            for (int dj = 0; dj < 3; ++dj)
                #pragma unroll
                for (int ic = 0; ic < 8; ++ic)
                    s += win[slot][dj][ic] * wr[ic][di * 3 + dj];
        }
        outp[((long)((b * HH + i0 + ii) * WW + j0)) * 24 + tid] = acc[ii] + s;
    }
    #undef LROW
}

// ---------------------------------------------------------------------------
extern "C" void kernel_launch(void* const* d_in, const int* in_sizes, int n_in,
                              void* d_out, int out_size, void* d_ws, size_t ws_size,
                              hipStream_t stream) {
    const float* x_in    = (const float*)d_in[0];
    const float* fea     = (const float*)d_in[1];
    const float* imap    = (const float*)d_in[2];
    const float* Wq      = (const float*)d_in[3];
    const float* Wk      = (const float*)d_in[4];
    const float* Wv      = (const float*)d_in[5];
    const float* rescale = (const float*)d_in[6];
    const float* Wp      = (const float*)d_in[7];
    const float* bp      = (const float*)d_in[8];
    const float* c1w     = (const float*)d_in[9];
    const float* c2w     = (const float*)d_in[10];
    float* out = (float*)d_out;

    float* ws      = (float*)d_ws;
    float* Sp_part = ws;                       // 256*1536 = 393,216 floats
    float* Sp2     = ws + 393216;              // 6,144 floats
    float* Pt      = ws + 399360;              // 6,144 floats
    int*   sync_   = (int*)(ws + 405504);      // 12 ints

    // zero all accumulators + counters (atomics accumulate across iterations)
    hipMemsetAsync(ws, 0, 405504 * sizeof(float) + 48, stream);
    mega<<<BB * 256, 192, 0, stream>>>(x_in, fea, imap, Wq, Wk, Wv, rescale,
                                       Wp, bp, c1w, c2w,
                                       Sp_part, Sp2, Pt, sync_, out);
}

// Round 7
// 315.385 us; speedup vs baseline: 1.3750x; 1.3750x over previous
//
#include <hip/hip_runtime.h>
#include <math.h>

#define HEADS 8
#define DIM   64
#define DK    24
#define DHK   3
#define BB    4
#define HH    128
#define WW    128
#define NN    (HH*WW)
#define QSCALE 0.125f

// ---------------------------------------------------------------------------
// K1 (R4-proven, verbatim + counter zeroing): token-partial reduce, plain
// stores only. grid 256 x 1024 thr, 16-wave LDS merge -> Sp_part[256][1536].
// Blocks 0-3 zero Pt; block 4 zeroes the done2 counters for K2.
// NO data atomics (R6 lesson: 1.57M atomicAdds -> 139MB write-through, 368us).
// ---------------------------------------------------------------------------
__global__ __launch_bounds__(1024) void s_reduce(
    const float* __restrict__ imap,   // [B*N,24]
    const float* __restrict__ x,      // [B*N,64]
    float* __restrict__ Sp_part,      // [256,1536]
    float* __restrict__ Pt,           // [4,1536] -> zeroed here
    int* __restrict__ sync_)          // [4] done2 -> zeroed here
{
    __shared__ float part[16 * 1540];   // 98.5 KB, stride 1540 (pad: %32==4)
    const int tid = threadIdx.x;
    const int blk = blockIdx.x;
    const int b = blk >> 6, chunk = blk & 63;
    const int w = tid >> 6, lane = tid & 63;
    const int cq = lane & 15;         // c = cq*4
    const int ig = lane >> 4;         // i = ig*6 .. +5

    const long tok0 = (long)b * NN + chunk * 256 + w * 16;
    const float* xp = x    + tok0 * 64 + cq * 4;
    const float* mp = imap + tok0 * 24 + ig * 6;

    float acc[6][4];
    #pragma unroll
    for (int r = 0; r < 6; ++r)
        #pragma unroll
        for (int q = 0; q < 4; ++q) acc[r][q] = 0.f;

    #pragma unroll 4
    for (int t = 0; t < 16; ++t) {
        float4 xv = *(const float4*)(xp + t * 64);
        float2 m0 = *(const float2*)(mp + t * 24);
        float2 m1 = *(const float2*)(mp + t * 24 + 2);
        float2 m2 = *(const float2*)(mp + t * 24 + 4);
        float mm[6] = {m0.x, m0.y, m1.x, m1.y, m2.x, m2.y};
        #pragma unroll
        for (int r = 0; r < 6; ++r) {
            acc[r][0] += mm[r] * xv.x;
            acc[r][1] += mm[r] * xv.y;
            acc[r][2] += mm[r] * xv.z;
            acc[r][3] += mm[r] * xv.w;
        }
    }

    float* pp = part + w * 1540;
    #pragma unroll
    for (int r = 0; r < 6; ++r) {
        float4 v = {acc[r][0], acc[r][1], acc[r][2], acc[r][3]};
        *(float4*)(pp + (ig * 6 + r) * 64 + cq * 4) = v;
    }
    __syncthreads();

    for (int e = tid; e < 1536; e += 1024) {
        float s = 0.f;
        #pragma unroll
        for (int ww = 0; ww < 16; ++ww) s += part[ww * 1540 + e];
        Sp_part[(long)blk * 1536 + e] = s;
    }
    if (blk < 4)
        for (int e = tid; e < 1536; e += 1024) Pt[blk * 1536 + e] = 0.f;
    if (blk == 4 && tid < 4) sync_[tid] = 0;
}

// ---------------------------------------------------------------------------
// K2: conv_fused (R4-proven v1 body, verbatim) + attention pre-phase on
// blocks chunk<8 (one per (b,h)). Kernel boundary after K1 makes Sp_part
// coherent (no producer spin). Producers: slab-reduce + R4-proven attention
// -> atomicAdd Pt (49K adds, harmless) -> done2[b]++. Everyone: ph1+ph2
// (Pt-independent, hides the attention tail), spin done2[b]==8 (mega-proven
// consumer pattern), ph3.
// Deadlock-free: LDS 27328B -> 5 blocks/CU -> 1280 >= 1024 grid => all
// blocks co-resident; producers never spin. __launch_bounds__(192,4) caps
// VGPR<=128 (mega compiled at 64) so LDS is the binding limit.
// ---------------------------------------------------------------------------
__global__ __launch_bounds__(192, 4) void conv_attn(
    const float* __restrict__ imap, const float* __restrict__ Wk,
    const float* __restrict__ c1w,  const float* __restrict__ fea,
    const float* __restrict__ c2w,  const float* __restrict__ bp,
    const float* __restrict__ Wq,   const float* __restrict__ Wv,
    const float* __restrict__ rescale, const float* __restrict__ Wp,
    const float* __restrict__ Sp_part, // [256,1536] from K1
    float* __restrict__ Pt,            // [4,1536] zeroed by K1
    int* __restrict__ done2,           // [4] zeroed by K1
    float* __restrict__ outp)
{
    __shared__ __align__(16) float smem[6832];  // attn 6144 / conv 6832

    const int tid = threadIdx.x;
    const int blk = blockIdx.x;
    const int b = blk >> 8, chunk = blk & 255;
    const int ti = chunk >> 4, tj = chunk & 15;
    const int i0 = ti * 8, j0 = tj * 8;

    // ======== attention pre-phase: blocks chunk<8, h = chunk ========
    if (chunk < 8) {
        const int h = chunk;
        float* Sp_l = smem;            // 1536
        float* sS   = smem + 1536;     // 192 (reused for M)
        float* sP   = smem + 1760;     // 192
        float* Wv_l = smem + 1984;     // 64*65 = 4160 -> ends 6144
        {   // reduce 64 slabs (plain reads; K1 boundary = coherence)
            const float* p = Sp_part + (long)(b * 64) * 1536 + tid * 8;
            float a2[8];
            #pragma unroll
            for (int q = 0; q < 8; ++q) a2[q] = 0.f;
            #pragma unroll 8
            for (int pb = 0; pb < 64; ++pb) {
                float4 u = *(const float4*)(p + (long)pb * 1536);
                float4 v = *(const float4*)(p + (long)pb * 1536 + 4);
                a2[0] += u.x; a2[1] += u.y; a2[2] += u.z; a2[3] += u.w;
                a2[4] += v.x; a2[5] += v.y; a2[6] += v.z; a2[7] += v.w;
            }
            #pragma unroll
            for (int q = 0; q < 8; ++q) Sp_l[tid * 8 + q] = a2[q];
        }
        for (int e = tid; e < 4096; e += 192) {
            int c = e >> 6, d = e & 63;
            Wv_l[c * 65 + d] = Wv[c * 512 + h * 64 + d];
        }
        __syncthreads();

        const int w3 = tid >> 6, lane = tid & 63;   // exactly 3 waves
        {   // S[ch,c] = sum_i Wk[i,ch]*Sp[i,c]
            const float* wk = Wk + (h * 3 + w3);
            float s = 0.f;
            #pragma unroll
            for (int i = 0; i < 24; ++i) s += wk[i * 24] * Sp_l[i * 64 + lane];
            sS[w3 * 64 + lane] = s;
        }
        __syncthreads();
        {   // att row + wave-parallel softmax over d = lane
            const float* sr = sS + w3 * 64;
            float a = 0.f;
            #pragma unroll 8
            for (int c = 0; c < 64; ++c) a += sr[c] * Wq[c * 512 + h * 64 + lane];
            a *= QSCALE * rescale[h];
            float mx = a;
            #pragma unroll
            for (int off = 32; off >= 1; off >>= 1)
                mx = fmaxf(mx, __shfl_xor(mx, off, 64));
            float e = expf(a - mx);
            float sum = e;
            #pragma unroll
            for (int off = 32; off >= 1; off >>= 1)
                sum += __shfl_xor(sum, off, 64);
            sP[w3 * 64 + lane] = e / sum;
        }
        __syncthreads();
        {   // M[ch,c] = sum_d P[ch,d]*Wv[c,h*64+d]; reuse sS
            const float* pr = sP + w3 * 64;
            const float* wv = Wv_l + lane * 65;
            float m = 0.f;
            #pragma unroll
            for (int d = 0; d < 64; ++d) m += pr[d] * wv[d];
            sS[w3 * 64 + lane] = m;
        }
        __syncthreads();
        for (int q = tid; q < 1536; q += 192) {
            int o = q >> 6, c = q & 63;
            float v = 0.f;
            #pragma unroll
            for (int k = 0; k < 3; ++k)
                v += sS[k * 64 + c] * Wp[(k * 8 + h) * 24 + o];
            atomicAdd(&Pt[b * 1536 + o * 64 + c], v);
        }
        __threadfence();               // release Pt before counter
        __syncthreads();               // all threads' adds done
        if (tid == 0) atomicAdd(&done2[b], 1);
        __syncthreads();               // smem reused by ph1 below
    }

    // ================= ph1: kproj on 12x12 halo (R4 v1, verbatim) ==========
    float* kbuf = smem;               // 144*28 = 4032
    float* y1l  = smem + 4032;        // 100*28 = 2800
    const int o = tid % 24, jj = tid / 24;
    const int g = o >> 3;

    if (tid < 144) {
        const int pi = tid / 12, pj = tid % 12;
        const int gi = i0 + pi - 2, gj = j0 + pj - 2;
        float kv[24];
        #pragma unroll
        for (int j = 0; j < 24; ++j) kv[j] = 0.f;
        if (gi >= 0 && gi < HH && gj >= 0 && gj < WW) {
            const float4* m4 = (const float4*)(imap + (((long)b * HH + gi) * WW + gj) * 24);
            float m[24];
            #pragma unroll
            for (int i = 0; i < 6; ++i) {
                float4 v = m4[i];
                m[4*i+0]=v.x; m[4*i+1]=v.y; m[4*i+2]=v.z; m[4*i+3]=v.w;
            }
            for (int i = 0; i < 24; ++i) {
                float mi = m[i];
                #pragma unroll
                for (int j = 0; j < 24; ++j) kv[j] += mi * Wk[i * 24 + j];
            }
        }
        #pragma unroll
        for (int j = 0; j < 24; ++j) kbuf[tid * 28 + j] = kv[j];
    }
    __syncthreads();

    // ================= ph2: y1 = gelu(conv1) (R4 v1, verbatim) =============
    {
        float wr[8][9];
        {
            const float4* wp = (const float4*)(c1w + o * 72);
            #pragma unroll
            for (int t = 0; t < 18; ++t) ((float4*)wr)[t] = wp[t];
        }
        for (int task = tid; task < 240; task += 192) {
            const int r = task / 24;
            float wc[3][3][8];
            #pragma unroll
            for (int slot = 0; slot < 2; ++slot)
                #pragma unroll
                for (int di = 0; di < 3; ++di) {
                    const float* p = kbuf + ((r + di) * 12 + slot) * 28 + g * 8;
                    *(float4*)&wc[slot][di][0] = *(const float4*)(p);
                    *(float4*)&wc[slot][di][4] = *(const float4*)(p + 4);
                }
            #pragma unroll
            for (int c = 0; c < 10; ++c) {
                const int s2 = (c + 2) % 3;
                #pragma unroll
                for (int di = 0; di < 3; ++di) {
                    const float* p = kbuf + ((r + di) * 12 + (c + 2)) * 28 + g * 8;
                    *(float4*)&wc[s2][di][0] = *(const float4*)(p);
                    *(float4*)&wc[s2][di][4] = *(const float4*)(p + 4);
                }
                float s = 0.f;
                #pragma unroll
                for (int dj = 0; dj < 3; ++dj) {
                    const int sl = (c + dj) % 3;
                    #pragma unroll
                    for (int di = 0; di < 3; ++di)
                        #pragma unroll
                        for (int ic = 0; ic < 8; ++ic)
                            s += wc[sl][di][ic] * wr[ic][di * 3 + dj];
                }
                const int gi = i0 + r - 1, gj = j0 + c - 1;
                float val = 0.f;
                if (gi >= 0 && gi < HH && gj >= 0 && gj < WW)
                    val = 0.5f * s * (1.f + erff(s * 0.70710678f));
                y1l[(r * 10 + c) * 28 + o] = val;
            }
        }
    }
    __syncthreads();

    // ===== wait for Pt (mega-proven consumer spin; ~0 wait by now) =========
    if (tid == 0)
        while (__hip_atomic_load(&done2[b], __ATOMIC_RELAXED, __HIP_MEMORY_SCOPE_AGENT) < 8)
            __builtin_amdgcn_s_sleep(2);
    __syncthreads();
    __threadfence();                  // acquire Pt

    // ================= ph3: proj + conv2 (R4 v1, verbatim) =================
    float wr[8][9];
    {
        const float4* wp = (const float4*)(c2w + o * 72);
        #pragma unroll
        for (int t = 0; t < 18; ++t) ((float4*)wr)[t] = wp[t];
    }

    float acc[8];
    {
        const float bo = bp[o];
        #pragma unroll
        for (int ii = 0; ii < 8; ++ii) acc[ii] = bo;
        const float* PtRow = Pt + b * 1536 + o * 64;
        const float* feaB = fea + (((long)(b * HH + i0)) * WW + (j0 + jj)) * 64;
        for (int cq = 0; cq < 16; ++cq) {
            float4 p = *(const float4*)(PtRow + cq * 4);
            #pragma unroll
            for (int ii = 0; ii < 8; ++ii) {
                float4 f = *(const float4*)(feaB + (long)ii * WW * 64 + cq * 4);
                acc[ii] += f.x * p.x + f.y * p.y + f.z * p.z + f.w * p.w;
            }
        }
    }

    float win[3][3][8];
    #define LROW(R, SLOT)                                                     \
    {                                                                         \
        const float* rp_ = y1l + ((R) * 10 + jj) * 28 + g * 8;                \
        *(float4*)&win[SLOT][0][0] = *(const float4*)(rp_);                   \
        *(float4*)&win[SLOT][0][4] = *(const float4*)(rp_ + 4);               \
        *(float4*)&win[SLOT][1][0] = *(const float4*)(rp_ + 28);              \
        *(float4*)&win[SLOT][1][4] = *(const float4*)(rp_ + 32);              \
        *(float4*)&win[SLOT][2][0] = *(const float4*)(rp_ + 56);              \
        *(float4*)&win[SLOT][2][4] = *(const float4*)(rp_ + 60);              \
    }

    LROW(0, 0)
    LROW(1, 1)
    #pragma unroll
    for (int ii = 0; ii < 8; ++ii) {
        LROW(ii + 2, (ii + 2) % 3)
        float s = 0.f;
        #pragma unroll
        for (int di = 0; di < 3; ++di) {
            const int slot = (ii + di) % 3;
            #pragma unroll
            for (int dj = 0; dj < 3; ++dj)
                #pragma unroll
                for (int ic = 0; ic < 8; ++ic)
                    s += win[slot][dj][ic] * wr[ic][di * 3 + dj];
        }
        outp[((long)((b * HH + i0 + ii) * WW + j0)) * 24 + tid] = acc[ii] + s;
    }
    #undef LROW
}

// ---------------------------------------------------------------------------
extern "C" void kernel_launch(void* const* d_in, const int* in_sizes, int n_in,
                              void* d_out, int out_size, void* d_ws, size_t ws_size,
                              hipStream_t stream) {
    const float* x_in    = (const float*)d_in[0];
    const float* fea     = (const float*)d_in[1];
    const float* imap    = (const float*)d_in[2];
    const float* Wq      = (const float*)d_in[3];
    const float* Wk      = (const float*)d_in[4];
    const float* Wv      = (const float*)d_in[5];
    const float* rescale = (const float*)d_in[6];
    const float* Wp      = (const float*)d_in[7];
    const float* bp      = (const float*)d_in[8];
    const float* c1w     = (const float*)d_in[9];
    const float* c2w     = (const float*)d_in[10];
    float* out = (float*)d_out;

    float* ws      = (float*)d_ws;
    float* Sp_part = ws;                       // 256*1536 = 393,216 floats
    float* Pt      = ws + 393216;              // 6,144 floats
    int*   sync_   = (int*)(ws + 399360);      // 4 ints (done2)

    s_reduce<<<256, 1024, 0, stream>>>(imap, x_in, Sp_part, Pt, sync_);
    conv_attn<<<BB * 256, 192, 0, stream>>>(imap, Wk, c1w, fea, c2w, bp,
                                            Wq, Wv, rescale, Wp,
                                            Sp_part, Pt, sync_, out);
}

// Round 8
// 208.799 us; speedup vs baseline: 2.0768x; 1.5105x over previous
//
#include <hip/hip_runtime.h>
#include <math.h>

#define HEADS 8
#define DIM   64
#define DK    24
#define DHK   3
#define BB    4
#define HH    128
#define WW    128
#define NN    (HH*WW)
#define QSCALE 0.125f

// ---------------------------------------------------------------------------
// K1 (R4-proven, verbatim): token-partial reduce, plain stores only.
// grid 256 x 1024 thr, 16-wave LDS merge -> Sp_part[256][1536].
// Blocks 0-3 zero Pt; block 4 zeroes done2.
// ---------------------------------------------------------------------------
__global__ __launch_bounds__(1024) void s_reduce(
    const float* __restrict__ imap,   // [B*N,24]
    const float* __restrict__ x,      // [B*N,64]
    float* __restrict__ Sp_part,      // [256,1536]
    float* __restrict__ Pt,           // [4,1536] -> zeroed here
    int* __restrict__ sync_)          // [4] done2 -> zeroed here
{
    __shared__ float part[16 * 1540];   // 98.5 KB, stride 1540 (pad: %32==4)
    const int tid = threadIdx.x;
    const int blk = blockIdx.x;
    const int b = blk >> 6, chunk = blk & 63;
    const int w = tid >> 6, lane = tid & 63;
    const int cq = lane & 15;         // c = cq*4
    const int ig = lane >> 4;         // i = ig*6 .. +5

    const long tok0 = (long)b * NN + chunk * 256 + w * 16;
    const float* xp = x    + tok0 * 64 + cq * 4;
    const float* mp = imap + tok0 * 24 + ig * 6;

    float acc[6][4];
    #pragma unroll
    for (int r = 0; r < 6; ++r)
        #pragma unroll
        for (int q = 0; q < 4; ++q) acc[r][q] = 0.f;

    #pragma unroll 4
    for (int t = 0; t < 16; ++t) {
        float4 xv = *(const float4*)(xp + t * 64);
        float2 m0 = *(const float2*)(mp + t * 24);
        float2 m1 = *(const float2*)(mp + t * 24 + 2);
        float2 m2 = *(const float2*)(mp + t * 24 + 4);
        float mm[6] = {m0.x, m0.y, m1.x, m1.y, m2.x, m2.y};
        #pragma unroll
        for (int r = 0; r < 6; ++r) {
            acc[r][0] += mm[r] * xv.x;
            acc[r][1] += mm[r] * xv.y;
            acc[r][2] += mm[r] * xv.z;
            acc[r][3] += mm[r] * xv.w;
        }
    }

    float* pp = part + w * 1540;
    #pragma unroll
    for (int r = 0; r < 6; ++r) {
        float4 v = {acc[r][0], acc[r][1], acc[r][2], acc[r][3]};
        *(float4*)(pp + (ig * 6 + r) * 64 + cq * 4) = v;
    }
    __syncthreads();

    for (int e = tid; e < 1536; e += 1024) {
        float s = 0.f;
        #pragma unroll
        for (int ww = 0; ww < 16; ++ww) s += part[ww * 1540 + e];
        Sp_part[(long)blk * 1536 + e] = s;
    }
    if (blk < 4)
        for (int e = tid; e < 1536; e += 1024) Pt[blk * 1536 + e] = 0.f;
    if (blk == 4 && tid < 4) sync_[tid] = 0;
}

// ---------------------------------------------------------------------------
// K2: conv + attention pre-phase (R7 structure). ONE change vs R7:
// __launch_bounds__(192,3) instead of (192,4). R7's (192,4) forced VGPR=64
// -> ph3's ~152 live floats spilled to scratch -> WRITE_SIZE 84.7MB (14x
// output), FETCH +50MB, 230us. (192,3) caps VGPR at ~168 (>> the ~90-100
// the R4 body actually uses, so no spill) while still guaranteeing
// 4 blocks/CU x 256 CU = 1024 >= grid -> consumer spin deadlock-free.
// LDS 27328B -> 5 blocks/CU (secondary limit).
// ---------------------------------------------------------------------------
__global__ __launch_bounds__(192, 3) void conv_attn(
    const float* __restrict__ imap, const float* __restrict__ Wk,
    const float* __restrict__ c1w,  const float* __restrict__ fea,
    const float* __restrict__ c2w,  const float* __restrict__ bp,
    const float* __restrict__ Wq,   const float* __restrict__ Wv,
    const float* __restrict__ rescale, const float* __restrict__ Wp,
    const float* __restrict__ Sp_part, // [256,1536] from K1
    float* __restrict__ Pt,            // [4,1536] zeroed by K1
    int* __restrict__ done2,           // [4] zeroed by K1
    float* __restrict__ outp)
{
    __shared__ __align__(16) float smem[6832];  // attn 6144 / conv 6832

    const int tid = threadIdx.x;
    const int blk = blockIdx.x;
    const int b = blk >> 8, chunk = blk & 255;
    const int ti = chunk >> 4, tj = chunk & 15;
    const int i0 = ti * 8, j0 = tj * 8;

    // ======== attention pre-phase: blocks chunk<8, h = chunk ========
    if (chunk < 8) {
        const int h = chunk;
        float* Sp_l = smem;            // 1536
        float* sS   = smem + 1536;     // 192 (reused for M)
        float* sP   = smem + 1760;     // 192
        float* Wv_l = smem + 1984;     // 64*65 = 4160 -> ends 6144
        {   // reduce 64 slabs (plain reads; K1 boundary = coherence)
            const float* p = Sp_part + (long)(b * 64) * 1536 + tid * 8;
            float a2[8];
            #pragma unroll
            for (int q = 0; q < 8; ++q) a2[q] = 0.f;
            #pragma unroll 8
            for (int pb = 0; pb < 64; ++pb) {
                float4 u = *(const float4*)(p + (long)pb * 1536);
                float4 v = *(const float4*)(p + (long)pb * 1536 + 4);
                a2[0] += u.x; a2[1] += u.y; a2[2] += u.z; a2[3] += u.w;
                a2[4] += v.x; a2[5] += v.y; a2[6] += v.z; a2[7] += v.w;
            }
            #pragma unroll
            for (int q = 0; q < 8; ++q) Sp_l[tid * 8 + q] = a2[q];
        }
        for (int e = tid; e < 4096; e += 192) {
            int c = e >> 6, d = e & 63;
            Wv_l[c * 65 + d] = Wv[c * 512 + h * 64 + d];
        }
        __syncthreads();

        const int w3 = tid >> 6, lane = tid & 63;   // exactly 3 waves
        {   // S[ch,c] = sum_i Wk[i,ch]*Sp[i,c]
            const float* wk = Wk + (h * 3 + w3);
            float s = 0.f;
            #pragma unroll
            for (int i = 0; i < 24; ++i) s += wk[i * 24] * Sp_l[i * 64 + lane];
            sS[w3 * 64 + lane] = s;
        }
        __syncthreads();
        {   // att row + wave-parallel softmax over d = lane
            const float* sr = sS + w3 * 64;
            float a = 0.f;
            #pragma unroll 8
            for (int c = 0; c < 64; ++c) a += sr[c] * Wq[c * 512 + h * 64 + lane];
            a *= QSCALE * rescale[h];
            float mx = a;
            #pragma unroll
            for (int off = 32; off >= 1; off >>= 1)
                mx = fmaxf(mx, __shfl_xor(mx, off, 64));
            float e = expf(a - mx);
            float sum = e;
            #pragma unroll
            for (int off = 32; off >= 1; off >>= 1)
                sum += __shfl_xor(sum, off, 64);
            sP[w3 * 64 + lane] = e / sum;
        }
        __syncthreads();
        {   // M[ch,c] = sum_d P[ch,d]*Wv[c,h*64+d]; reuse sS
            const float* pr = sP + w3 * 64;
            const float* wv = Wv_l + lane * 65;
            float m = 0.f;
            #pragma unroll
            for (int d = 0; d < 64; ++d) m += pr[d] * wv[d];
            sS[w3 * 64 + lane] = m;
        }
        __syncthreads();
        for (int q = tid; q < 1536; q += 192) {
            int o = q >> 6, c = q & 63;
            float v = 0.f;
            #pragma unroll
            for (int k = 0; k < 3; ++k)
                v += sS[k * 64 + c] * Wp[(k * 8 + h) * 24 + o];
            atomicAdd(&Pt[b * 1536 + o * 64 + c], v);
        }
        __threadfence();               // release Pt before counter
        __syncthreads();               // all threads' adds done
        if (tid == 0) atomicAdd(&done2[b], 1);
        __syncthreads();               // smem reused by ph1 below
    }

    // ================= ph1: kproj on 12x12 halo (R4 v1, verbatim) ==========
    float* kbuf = smem;               // 144*28 = 4032
    float* y1l  = smem + 4032;        // 100*28 = 2800
    const int o = tid % 24, jj = tid / 24;
    const int g = o >> 3;

    if (tid < 144) {
        const int pi = tid / 12, pj = tid % 12;
        const int gi = i0 + pi - 2, gj = j0 + pj - 2;
        float kv[24];
        #pragma unroll
        for (int j = 0; j < 24; ++j) kv[j] = 0.f;
        if (gi >= 0 && gi < HH && gj >= 0 && gj < WW) {
            const float4* m4 = (const float4*)(imap + (((long)b * HH + gi) * WW + gj) * 24);
            float m[24];
            #pragma unroll
            for (int i = 0; i < 6; ++i) {
                float4 v = m4[i];
                m[4*i+0]=v.x; m[4*i+1]=v.y; m[4*i+2]=v.z; m[4*i+3]=v.w;
            }
            for (int i = 0; i < 24; ++i) {
                float mi = m[i];
                #pragma unroll
                for (int j = 0; j < 24; ++j) kv[j] += mi * Wk[i * 24 + j];
            }
        }
        #pragma unroll
        for (int j = 0; j < 24; ++j) kbuf[tid * 28 + j] = kv[j];
    }
    __syncthreads();

    // ================= ph2: y1 = gelu(conv1) (R4 v1, verbatim) =============
    {
        float wr[8][9];
        {
            const float4* wp = (const float4*)(c1w + o * 72);
            #pragma unroll
            for (int t = 0; t < 18; ++t) ((float4*)wr)[t] = wp[t];
        }
        for (int task = tid; task < 240; task += 192) {
            const int r = task / 24;
            float wc[3][3][8];
            #pragma unroll
            for (int slot = 0; slot < 2; ++slot)
                #pragma unroll
                for (int di = 0; di < 3; ++di) {
                    const float* p = kbuf + ((r + di) * 12 + slot) * 28 + g * 8;
                    *(float4*)&wc[slot][di][0] = *(const float4*)(p);
                    *(float4*)&wc[slot][di][4] = *(const float4*)(p + 4);
                }
            #pragma unroll
            for (int c = 0; c < 10; ++c) {
                const int s2 = (c + 2) % 3;
                #pragma unroll
                for (int di = 0; di < 3; ++di) {
                    const float* p = kbuf + ((r + di) * 12 + (c + 2)) * 28 + g * 8;
                    *(float4*)&wc[s2][di][0] = *(const float4*)(p);
                    *(float4*)&wc[s2][di][4] = *(const float4*)(p + 4);
                }
                float s = 0.f;
                #pragma unroll
                for (int dj = 0; dj < 3; ++dj) {
                    const int sl = (c + dj) % 3;
                    #pragma unroll
                    for (int di = 0; di < 3; ++di)
                        #pragma unroll
                        for (int ic = 0; ic < 8; ++ic)
                            s += wc[sl][di][ic] * wr[ic][di * 3 + dj];
                }
                const int gi = i0 + r - 1, gj = j0 + c - 1;
                float val = 0.f;
                if (gi >= 0 && gi < HH && gj >= 0 && gj < WW)
                    val = 0.5f * s * (1.f + erff(s * 0.70710678f));
                y1l[(r * 10 + c) * 28 + o] = val;
            }
        }
    }
    __syncthreads();

    // ===== wait for Pt (mega-proven consumer spin; ~0 wait by now) =========
    if (tid == 0)
        while (__hip_atomic_load(&done2[b], __ATOMIC_RELAXED, __HIP_MEMORY_SCOPE_AGENT) < 8)
            __builtin_amdgcn_s_sleep(2);
    __syncthreads();
    __threadfence();                  // acquire Pt

    // ================= ph3: proj + conv2 (R4 v1, verbatim) =================
    float wr[8][9];
    {
        const float4* wp = (const float4*)(c2w + o * 72);
        #pragma unroll
        for (int t = 0; t < 18; ++t) ((float4*)wr)[t] = wp[t];
    }

    float acc[8];
    {
        const float bo = bp[o];
        #pragma unroll
        for (int ii = 0; ii < 8; ++ii) acc[ii] = bo;
        const float* PtRow = Pt + b * 1536 + o * 64;
        const float* feaB = fea + (((long)(b * HH + i0)) * WW + (j0 + jj)) * 64;
        for (int cq = 0; cq < 16; ++cq) {
            float4 p = *(const float4*)(PtRow + cq * 4);
            #pragma unroll
            for (int ii = 0; ii < 8; ++ii) {
                float4 f = *(const float4*)(feaB + (long)ii * WW * 64 + cq * 4);
                acc[ii] += f.x * p.x + f.y * p.y + f.z * p.z + f.w * p.w;
            }
        }
    }

    float win[3][3][8];
    #define LROW(R, SLOT)                                                     \
    {                                                                         \
        const float* rp_ = y1l + ((R) * 10 + jj) * 28 + g * 8;                \
        *(float4*)&win[SLOT][0][0] = *(const float4*)(rp_);                   \
        *(float4*)&win[SLOT][0][4] = *(const float4*)(rp_ + 4);               \
        *(float4*)&win[SLOT][1][0] = *(const float4*)(rp_ + 28);              \
        *(float4*)&win[SLOT][1][4] = *(const float4*)(rp_ + 32);              \
        *(float4*)&win[SLOT][2][0] = *(const float4*)(rp_ + 56);              \
        *(float4*)&win[SLOT][2][4] = *(const float4*)(rp_ + 60);              \
    }

    LROW(0, 0)
    LROW(1, 1)
    #pragma unroll
    for (int ii = 0; ii < 8; ++ii) {
        LROW(ii + 2, (ii + 2) % 3)
        float s = 0.f;
        #pragma unroll
        for (int di = 0; di < 3; ++di) {
            const int slot = (ii + di) % 3;
            #pragma unroll
            for (int dj = 0; dj < 3; ++dj)
                #pragma unroll
                for (int ic = 0; ic < 8; ++ic)
                    s += win[slot][dj][ic] * wr[ic][di * 3 + dj];
        }
        outp[((long)((b * HH + i0 + ii) * WW + j0)) * 24 + tid] = acc[ii] + s;
    }
    #undef LROW
}

// ---------------------------------------------------------------------------
extern "C" void kernel_launch(void* const* d_in, const int* in_sizes, int n_in,
                              void* d_out, int out_size, void* d_ws, size_t ws_size,
                              hipStream_t stream) {
    const float* x_in    = (const float*)d_in[0];
    const float* fea     = (const float*)d_in[1];
    const float* imap    = (const float*)d_in[2];
    const float* Wq      = (const float*)d_in[3];
    const float* Wk      = (const float*)d_in[4];
    const float* Wv      = (const float*)d_in[5];
    const float* rescale = (const float*)d_in[6];
    const float* Wp      = (const float*)d_in[7];
    const float* bp      = (const float*)d_in[8];
    const float* c1w     = (const float*)d_in[9];
    const float* c2w     = (const float*)d_in[10];
    float* out = (float*)d_out;

    float* ws      = (float*)d_ws;
    float* Sp_part = ws;                       // 256*1536 = 393,216 floats
    float* Pt      = ws + 393216;              // 6,144 floats
    int*   sync_   = (int*)(ws + 399360);      // 4 ints (done2)

    s_reduce<<<256, 1024, 0, stream>>>(imap, x_in, Sp_part, Pt, sync_);
    conv_attn<<<BB * 256, 192, 0, stream>>>(imap, Wk, c1w, fea, c2w, bp,
                                            Wq, Wv, rescale, Wp,
                                            Sp_part, Pt, sync_, out);
}

// Round 9
// 152.414 us; speedup vs baseline: 2.8451x; 1.3699x over previous
//
#include <hip/hip_runtime.h>
#include <math.h>

#define HEADS 8
#define DIM   64
#define DK    24
#define DHK   3
#define BB    4
#define HH    128
#define WW    128
#define NN    (HH*WW)
#define QSCALE 0.125f

// ---------------------------------------------------------------------------
// K1 (R4-proven, verbatim): token-partial reduce, plain stores only.
// grid 256 x 1024 thr, 16-wave LDS merge -> Sp_part[256][1536].
// Blocks 0-3 zero Pt for K2's atomicAdd.
// ---------------------------------------------------------------------------
__global__ __launch_bounds__(1024) void s_reduce(
    const float* __restrict__ imap,   // [B*N,24]
    const float* __restrict__ x,      // [B*N,64]
    float* __restrict__ Sp_part,      // [256,1536]
    float* __restrict__ Pt)           // [4,1536] -> zeroed here
{
    __shared__ float part[16 * 1540];   // 98.5 KB, stride 1540 (pad: %32==4)
    const int tid = threadIdx.x;
    const int blk = blockIdx.x;
    const int b = blk >> 6, chunk = blk & 63;
    const int w = tid >> 6, lane = tid & 63;
    const int cq = lane & 15;         // c = cq*4
    const int ig = lane >> 4;         // i = ig*6 .. +5

    const long tok0 = (long)b * NN + chunk * 256 + w * 16;
    const float* xp = x    + tok0 * 64 + cq * 4;
    const float* mp = imap + tok0 * 24 + ig * 6;

    float acc[6][4];
    #pragma unroll
    for (int r = 0; r < 6; ++r)
        #pragma unroll
        for (int q = 0; q < 4; ++q) acc[r][q] = 0.f;

    #pragma unroll 4
    for (int t = 0; t < 16; ++t) {
        float4 xv = *(const float4*)(xp + t * 64);
        float2 m0 = *(const float2*)(mp + t * 24);
        float2 m1 = *(const float2*)(mp + t * 24 + 2);
        float2 m2 = *(const float2*)(mp + t * 24 + 4);
        float mm[6] = {m0.x, m0.y, m1.x, m1.y, m2.x, m2.y};
        #pragma unroll
        for (int r = 0; r < 6; ++r) {
            acc[r][0] += mm[r] * xv.x;
            acc[r][1] += mm[r] * xv.y;
            acc[r][2] += mm[r] * xv.z;
            acc[r][3] += mm[r] * xv.w;
        }
    }

    float* pp = part + w * 1540;
    #pragma unroll
    for (int r = 0; r < 6; ++r) {
        float4 v = {acc[r][0], acc[r][1], acc[r][2], acc[r][3]};
        *(float4*)(pp + (ig * 6 + r) * 64 + cq * 4) = v;
    }
    __syncthreads();

    for (int e = tid; e < 1536; e += 1024) {
        float s = 0.f;
        #pragma unroll
        for (int ww = 0; ww < 16; ++ww) s += part[ww * 1540 + e];
        Sp_part[(long)blk * 1536 + e] = s;
    }
    if (blk < 4)
        for (int e = tid; e < 1536; e += 1024) Pt[blk * 1536 + e] = 0.f;
}

// ---------------------------------------------------------------------------
// K2 (R4-proven, verbatim): per-(b,h) slab reduce + attention. grid 32 x 256.
// ---------------------------------------------------------------------------
__global__ __launch_bounds__(256) void attn_fused(
    const float* __restrict__ Sp_part, // [256,1536]
    const float* __restrict__ Wk,      // [24,24]
    const float* __restrict__ Wq,      // [64,512]
    const float* __restrict__ Wv,      // [64,512]
    const float* __restrict__ rescale, // [8]
    const float* __restrict__ Wp,      // [24,24]
    float* __restrict__ Pt)            // [4,1536] pre-zeroed by K1
{
    __shared__ float Sp_l[1536];
    __shared__ float sS[192];        // S rows (reused for M)
    __shared__ float sP[192];        // softmax'd rows
    __shared__ float Wv_l[64 * 65];  // Wv[:, h*64..+63], stride 65

    const int tid = threadIdx.x, blk = blockIdx.x;
    const int b = blk >> 3, h = blk & 7;
    const int w = tid >> 6, lane = tid & 63;

    {
        float s[6] = {0.f, 0.f, 0.f, 0.f, 0.f, 0.f};
        const float* p = Sp_part + (long)(b * 64) * 1536 + tid;
        #pragma unroll 8
        for (int pb = 0; pb < 64; ++pb)
            #pragma unroll
            for (int k = 0; k < 6; ++k)
                s[k] += p[(long)pb * 1536 + k * 256];
        #pragma unroll
        for (int k = 0; k < 6; ++k) Sp_l[tid + k * 256] = s[k];
    }
    for (int e = tid; e < 4096; e += 256) {
        int c = e >> 6, d = e & 63;
        Wv_l[c * 65 + d] = Wv[c * 512 + h * 64 + d];
    }
    __syncthreads();

    if (w < 3) {
        const float* wk = Wk + (h * 3 + w);
        float s = 0.f;
        #pragma unroll
        for (int i = 0; i < 24; ++i) s += wk[i * 24] * Sp_l[i * 64 + lane];
        sS[w * 64 + lane] = s;
    }
    __syncthreads();

    if (w < 3) {
        const float* wq = Wq + h * 64 + lane;
        const float* sr = sS + w * 64;
        float a = 0.f;
        #pragma unroll 8
        for (int c = 0; c < 64; ++c) a += sr[c] * wq[c * 512];
        a *= QSCALE * rescale[h];
        float mx = a;
        #pragma unroll
        for (int off = 32; off >= 1; off >>= 1)
            mx = fmaxf(mx, __shfl_xor(mx, off, 64));
        float e = expf(a - mx);
        float sum = e;
        #pragma unroll
        for (int off = 32; off >= 1; off >>= 1)
            sum += __shfl_xor(sum, off, 64);
        sP[w * 64 + lane] = e / sum;
    }
    __syncthreads();

    if (w < 3) {
        const float* pr = sP + w * 64;
        const float* wv = Wv_l + lane * 65;
        float m = 0.f;
        #pragma unroll
        for (int d = 0; d < 64; ++d) m += pr[d] * wv[d];
        sS[w * 64 + lane] = m;
    }
    __syncthreads();

    for (int q = tid; q < 1536; q += 256) {
        int o = q >> 6, c = q & 63;
        float v = 0.f;
        #pragma unroll
        for (int k = 0; k < 3; ++k)
            v += sS[k * 64 + c] * Wp[(k * 8 + h) * 24 + o];
        atomicAdd(&Pt[b * 1536 + o * 64 + c], v);
    }
}

// ---------------------------------------------------------------------------
// K3 v4: R4 conv body, ph3 projection restructured. The standalone body's
// 70% stall was ph3's ~25K redundant global fea loads per block (24 threads
// share each value). Now: after ph2, cooperatively stage the 8x8x64 fea
// tile (coalesced, padded stride 68 -> conflict-free b128 reads) and the
// Pt batch row into LDS; compute proj from LDS. Global loads on that path:
// 25K -> 1.4K per block. LDS 35.1KB -> 4 blocks/CU.
// smem layout: [0..4352) fea tile (ph1/2 reuse [0..4032) as kbuf)
//              [4352..7152) y1l   [7152..8784) Pt row (stride 68)
// ---------------------------------------------------------------------------
__global__ __launch_bounds__(192, 2) void conv_fused(
    const float* __restrict__ imap, const float* __restrict__ Wk,
    const float* __restrict__ c1w,  const float* __restrict__ fea,
    const float* __restrict__ c2w,  const float* __restrict__ Pt,
    const float* __restrict__ bp,   float* __restrict__ outp)
{
    __shared__ __align__(16) float smem[8784];
    float* kbuf = smem;               // ph1/ph2: 144*28 = 4032
    float* feat = smem;               // ph3: 64 pix * 68 = 4352 (reuses kbuf)
    float* y1l  = smem + 4352;        // 100*28 = 2800
    float* ptl  = smem + 7152;        // 24*68 = 1632

    const int tid = threadIdx.x;
    const int blk = blockIdx.x;
    const int b = blk >> 8, ti = (blk >> 4) & 15, tj = blk & 15;
    const int i0 = ti * 8, j0 = tj * 8;
    const int o = tid % 24, jj = tid / 24;   // o: out-channel; jj: 0..7
    const int g = o >> 3;

    // ---- phase 1: kproj on the 12x12 halo (threads 0..143) ----
    if (tid < 144) {
        const int pi = tid / 12, pj = tid % 12;
        const int gi = i0 + pi - 2, gj = j0 + pj - 2;
        float kv[24];
        #pragma unroll
        for (int j = 0; j < 24; ++j) kv[j] = 0.f;
        if (gi >= 0 && gi < HH && gj >= 0 && gj < WW) {
            const float4* m4 = (const float4*)(imap + (((long)b * HH + gi) * WW + gj) * 24);
            float m[24];
            #pragma unroll
            for (int i = 0; i < 6; ++i) {
                float4 v = m4[i];
                m[4*i+0]=v.x; m[4*i+1]=v.y; m[4*i+2]=v.z; m[4*i+3]=v.w;
            }
            for (int i = 0; i < 24; ++i) {
                float mi = m[i];
                #pragma unroll
                for (int j = 0; j < 24; ++j) kv[j] += mi * Wk[i * 24 + j];
            }
        }
        #pragma unroll
        for (int j = 0; j < 24; ++j) kbuf[tid * 28 + j] = kv[j];
    }
    __syncthreads();

    // ---- phase 2: y1 = gelu(conv1) on 10x10 -> y1l ----
    {
        float wr[8][9];   // wr[ic][di*3+dj], OIHW-linear
        {
            const float4* wp = (const float4*)(c1w + o * 72);
            #pragma unroll
            for (int t = 0; t < 18; ++t) ((float4*)wr)[t] = wp[t];
        }
        for (int task = tid; task < 240; task += 192) {
            const int r = task / 24;           // y1l row 0..9
            float wc[3][3][8];                 // [col slot][di][ic]
            #pragma unroll
            for (int slot = 0; slot < 2; ++slot)
                #pragma unroll
                for (int di = 0; di < 3; ++di) {
                    const float* p = kbuf + ((r + di) * 12 + slot) * 28 + g * 8;
                    *(float4*)&wc[slot][di][0] = *(const float4*)(p);
                    *(float4*)&wc[slot][di][4] = *(const float4*)(p + 4);
                }
            #pragma unroll
            for (int c = 0; c < 10; ++c) {
                const int s2 = (c + 2) % 3;
                #pragma unroll
                for (int di = 0; di < 3; ++di) {
                    const float* p = kbuf + ((r + di) * 12 + (c + 2)) * 28 + g * 8;
                    *(float4*)&wc[s2][di][0] = *(const float4*)(p);
                    *(float4*)&wc[s2][di][4] = *(const float4*)(p + 4);
                }
                float s = 0.f;
                #pragma unroll
                for (int dj = 0; dj < 3; ++dj) {
                    const int sl = (c + dj) % 3;
                    #pragma unroll
                    for (int di = 0; di < 3; ++di)
                        #pragma unroll
                        for (int ic = 0; ic < 8; ++ic)
                            s += wc[sl][di][ic] * wr[ic][di * 3 + dj];
                }
                const int gi = i0 + r - 1, gj = j0 + c - 1;
                float val = 0.f;
                if (gi >= 0 && gi < HH && gj >= 0 && gj < WW)
                    val = 0.5f * s * (1.f + erff(s * 0.70710678f));
                y1l[(r * 10 + c) * 28 + o] = val;
            }
        }
    }
    __syncthreads();   // kbuf dead; feat may now overwrite it

    // ---- phase 3a: stage fea tile + Pt row into LDS (coalesced) ----
    {
        const float4* feaT4 = (const float4*)(fea + (((long)(b * HH + i0)) * WW + j0) * 64);
        float4* feat4 = (float4*)feat;
        for (int e = tid; e < 1024; e += 192) {
            const int pix = e >> 4, cq = e & 15;      // pix = ii*8+jj
            feat4[pix * 17 + cq] =
                feaT4[((long)(pix >> 3) * WW + (pix & 7)) * 16 + cq];
        }
        const float4* Pt4 = (const float4*)(Pt + b * 1536);
        float4* ptl4 = (float4*)ptl;
        for (int e = tid; e < 384; e += 192) {
            const int o2 = e >> 4, cq = e & 15;
            ptl4[o2 * 17 + cq] = Pt4[o2 * 16 + cq];
        }
    }
    __syncthreads();

    // ---- phase 3b: proj from LDS + conv2(y1l) ----
    float wr[8][9];
    {
        const float4* wp = (const float4*)(c2w + o * 72);
        #pragma unroll
        for (int t = 0; t < 18; ++t) ((float4*)wr)[t] = wp[t];
    }

    float acc[8];
    {
        const float bo = bp[o];
        #pragma unroll
        for (int ii = 0; ii < 8; ++ii) acc[ii] = bo;
        const float4* pr4 = (const float4*)(ptl + o * 68);
        for (int cq = 0; cq < 16; ++cq) {
            float4 p = pr4[cq];
            #pragma unroll
            for (int ii = 0; ii < 8; ++ii) {
                float4 f = ((const float4*)(feat + (ii * 8 + jj) * 68))[cq];
                acc[ii] += f.x * p.x + f.y * p.y + f.z * p.z + f.w * p.w;
            }
        }
    }

    float win[3][3][8];   // [row slot][dj][ic]
    #define LROW(R, SLOT)                                                     \
    {                                                                         \
        const float* rp_ = y1l + ((R) * 10 + jj) * 28 + g * 8;                \
        *(float4*)&win[SLOT][0][0] = *(const float4*)(rp_);                   \
        *(float4*)&win[SLOT][0][4] = *(const float4*)(rp_ + 4);               \
        *(float4*)&win[SLOT][1][0] = *(const float4*)(rp_ + 28);              \
        *(float4*)&win[SLOT][1][4] = *(const float4*)(rp_ + 32);              \
        *(float4*)&win[SLOT][2][0] = *(const float4*)(rp_ + 56);              \
        *(float4*)&win[SLOT][2][4] = *(const float4*)(rp_ + 60);              \
    }

    LROW(0, 0)
    LROW(1, 1)
    #pragma unroll
    for (int ii = 0; ii < 8; ++ii) {
        LROW(ii + 2, (ii + 2) % 3)
        float s = 0.f;
        #pragma unroll
        for (int di = 0; di < 3; ++di) {
            const int slot = (ii + di) % 3;
            #pragma unroll
            for (int dj = 0; dj < 3; ++dj)
                #pragma unroll
                for (int ic = 0; ic < 8; ++ic)
                    s += win[slot][dj][ic] * wr[ic][di * 3 + dj];
        }
        outp[((long)((b * HH + i0 + ii) * WW + j0)) * 24 + tid] = acc[ii] + s;
    }
    #undef LROW
}

// ---------------------------------------------------------------------------
extern "C" void kernel_launch(void* const* d_in, const int* in_sizes, int n_in,
                              void* d_out, int out_size, void* d_ws, size_t ws_size,
                              hipStream_t stream) {
    const float* x_in    = (const float*)d_in[0];
    const float* fea     = (const float*)d_in[1];
    const float* imap    = (const float*)d_in[2];
    const float* Wq      = (const float*)d_in[3];
    const float* Wk      = (const float*)d_in[4];
    const float* Wv      = (const float*)d_in[5];
    const float* rescale = (const float*)d_in[6];
    const float* Wp      = (const float*)d_in[7];
    const float* bp      = (const float*)d_in[8];
    const float* c1w     = (const float*)d_in[9];
    const float* c2w     = (const float*)d_in[10];
    float* out = (float*)d_out;

    float* ws      = (float*)d_ws;
    float* Sp_part = ws;                     // 256*1536 = 393,216 floats
    float* Pt      = ws + 393216;            // 6,144 floats

    s_reduce<<<256, 1024, 0, stream>>>(imap, x_in, Sp_part, Pt);
    attn_fused<<<32, 256, 0, stream>>>(Sp_part, Wk, Wq, Wv, rescale, Wp, Pt);
    conv_fused<<<BB * 256, 192, 0, stream>>>(imap, Wk, c1w, fea, c2w, Pt, bp, out);
}